// Round 1
// 132.655 us; speedup vs baseline: 1.0010x; 1.0010x over previous
//
#include <hip/hip_runtime.h>

#define DEG 3
#define NSAMP 20
#define BROWS 65536
#define NKNOT 64
#define ROWS_PER_BLOCK 8
#define THREADS 320                        /* 5 waves = 8 rows x 40 evals */
#define NBLOCKS (BROWS / ROWS_PER_BLOCK)   /* 8192 */
#define SEG 196  /* 192 floats per (row,tensor) segment, padded to 196 (float4-aligned, rotates banks by 4 per segment) */

// One eval (row, tensor, sample) per thread: 320 threads = 8 rows x 2 tensors x 20 samples.
// 100% lane utilization in the compute phase (was 40/64), waves cut 65536 -> 40960.
__global__ __launch_bounds__(THREADS) void bspline_loss_main(
    const float* __restrict__ pred, const float* __restrict__ tru,
    float* __restrict__ partials)
{
    __shared__ float lds[ROWS_PER_BLOCK * 2 * SEG];   // 12544 B
    __shared__ float sx[ROWS_PER_BLOCK * 40];         // per-eval results for pred/true pairing
    __shared__ float sy[ROWS_PER_BLOCK * 40];
    __shared__ float wsum[THREADS / 64];

    const int tid = threadIdx.x;

    // ---- stage 8 rows x 2 tensors into LDS; rows are contiguous in global,
    //      so each tensor is 384 contiguous float4 -> fully coalesced ----
    {
        const float4* p4 = (const float4*)(pred + (size_t)blockIdx.x * (ROWS_PER_BLOCK * 192));
        const float4* t4 = (const float4*)(tru  + (size_t)blockIdx.x * (ROWS_PER_BLOCK * 192));
        for (int i = tid; i < ROWS_PER_BLOCK * 48; i += THREADS) {
            const int r = i / 48;
            const int j = i - r * 48;
            ((float4*)(lds + (r * 2 + 0) * SEG))[j] = p4[i];
            ((float4*)(lds + (r * 2 + 1) * SEG))[j] = t4[i];
        }
    }
    __syncthreads();

    // ---- one spline evaluation per thread ----
    const int rloc = tid / 40;
    const int rem  = tid - rloc * 40;
    const int sel  = (rem >= 20) ? 1 : 0;     // 0 = pred, 1 = true
    const int s    = rem - sel * 20;          // sample index 0..19
    const float* d = lds + (rloc * 2 + sel) * SEG;   // [64] x (knot, cx, cy)

    // low = 0 always (kf[3] is a leading zero); high = knots[60]
    const float high = d[3 * 60];
    const float t = ((float)s * (1.0f / 19.0f)) * high;

    // cnt = upper_bound over knots[0..59]; base control-point index = cnt
    int lo = 0, hi = 60;
    while (lo < hi) {                          // uniform 6 iterations, no divergence
        int mid = (lo + hi) >> 1;
        if (d[3 * mid] <= t) lo = mid + 1; else hi = mid;
    }
    const int cnt = lo;

    float px[4], py[4], pw[4];
    #pragma unroll
    for (int k = 0; k < 4; ++k) {
        px[k] = d[3 * (cnt + k) + 1];
        py[k] = d[3 * (cnt + k) + 2];
        pw[k] = 1.0f;
    }
    // kf[m] = (m < 4) ? 0 : knots[m-4].  Note i1 = cnt+k+(4-l) >= cnt+4 >= 4 always,
    // so the kj zero-guard is provably dead and dropped.
    #pragma unroll
    for (int l = 1; l <= DEG; ++l) {
        #pragma unroll
        for (int k = DEG; k >= l; --k) {
            const int i0 = cnt + k;
            const int i1 = cnt + k + (DEG + 1 - l);
            const float ki = (i0 < 4) ? 0.f : d[3 * (i0 - 4)];
            const float kj = d[3 * (i1 - 4)];
            const float denom = kj - ki;
            const float alpha = (denom != 0.f) ? (t - ki) / denom : 0.f;
            const float b0 = 1.0f - alpha;
            px[k] = b0 * px[k - 1] + alpha * px[k];
            py[k] = b0 * py[k - 1] + alpha * py[k];
            pw[k] = b0 * pw[k - 1] + alpha * pw[k];
        }
    }
    const float rx = px[DEG] / pw[DEG];
    const float ry = py[DEG] / pw[DEG];

    // ---- pair pred (sel=0) with true (sel=1): partner is tid+20, may cross waves -> LDS ----
    sx[tid] = rx;
    sy[tid] = ry;
    __syncthreads();

    float acc = 0.f;
    if (!sel) {
        const float dx = rx - sx[tid + 20];
        const float dy = ry - sy[tid + 20];
        acc = dx * dx + dy * dy;
    }
    #pragma unroll
    for (int off = 32; off >= 1; off >>= 1)
        acc += __shfl_down(acc, off, 64);
    if ((tid & 63) == 0) wsum[tid >> 6] = acc;
    __syncthreads();
    if (tid == 0)
        partials[blockIdx.x] = wsum[0] + wsum[1] + wsum[2] + wsum[3] + wsum[4];
}

__global__ __launch_bounds__(256) void bspline_loss_reduce(
    const float* __restrict__ partials, float* __restrict__ out)
{
    const int tid = threadIdx.x;
    double acc = 0.0;
    const float4* p4 = (const float4*)partials;
    #pragma unroll 4
    for (int i = tid; i < NBLOCKS / 4; i += 256) {
        const float4 v = p4[i];
        acc += (double)v.x + (double)v.y + (double)v.z + (double)v.w;
    }
    #pragma unroll
    for (int off = 32; off >= 1; off >>= 1)
        acc += __shfl_down(acc, off, 64);
    __shared__ double ws[4];
    if ((tid & 63) == 0) ws[tid >> 6] = acc;
    __syncthreads();
    if (tid == 0) {
        const double tot = ws[0] + ws[1] + ws[2] + ws[3];
        out[0] = (float)(tot / (double)((long long)BROWS * NSAMP));
    }
}

extern "C" void kernel_launch(void* const* d_in, const int* in_sizes, int n_in,
                              void* d_out, int out_size, void* d_ws, size_t ws_size,
                              hipStream_t stream) {
    const float* pred = (const float*)d_in[0];
    const float* tru  = (const float*)d_in[1];
    // d_in[2] (true_masks) is ignored: reference uses mask = ones.
    float* out      = (float*)d_out;
    float* partials = (float*)d_ws;   // 8192 floats = 32 KB

    bspline_loss_main<<<NBLOCKS, THREADS, 0, stream>>>(pred, tru, partials);
    bspline_loss_reduce<<<1, 256, 0, stream>>>(partials, out);
}